// Round 12
// baseline (578.908 us; speedup 1.0000x reference)
//
#include <hip/hip_runtime.h>
#include <hip/hip_bf16.h>

// Problem constants: B=2, S=2048, D=1024, H=16, HD=64
typedef unsigned short u16;
typedef unsigned int u32;
typedef unsigned long long u64;
typedef _Float16 f16;
typedef __attribute__((__ext_vector_type__(4))) _Float16 f16x4;  // 8B
typedef __attribute__((__ext_vector_type__(8))) short bf16x8;    // 8 bf16 (4 VGPRs)
typedef __attribute__((__ext_vector_type__(4))) float f32x4;     // 16x16 C/D frag
typedef __attribute__((__ext_vector_type__(16))) float f32x16;   // 32x32 C/D frag
typedef __attribute__((__ext_vector_type__(2))) int i32x2;

__device__ __forceinline__ u16 f2bf(float f) {
    u32 u = __float_as_uint(f);
    return (u16)((u + 0x7fffu + ((u >> 16) & 1u)) >> 16);  // RNE
}

// ---------------------------------------------------------------------------
// Kernel 1 (fused): blocks 0..2047 = fp32->bf16 cvt of x + weights (x4
// grid-stride); blocks 2048..10239 = pack M into transposed bitmask, 4
// ballot-words per wave.
// Mb2[(b*32+w)*2048+q] bit i = (M[b][q][w*64+i] != 0).
// ---------------------------------------------------------------------------
__global__ __launch_bounds__(256) void prep_kernel(
    const float4* __restrict__ x,  const float4* __restrict__ wq,
    const float4* __restrict__ wk, const float4* __restrict__ wv,
    const float4* __restrict__ wo,
    u16* __restrict__ xb, u16* __restrict__ wqb, u16* __restrict__ wkb,
    u16* __restrict__ wvb, u16* __restrict__ wob,
    const int* __restrict__ M, u64* __restrict__ Mb2)
{
    if (blockIdx.x < 2048) {
        #pragma unroll
        for (int it = 0; it < 4; it++) {
            int gid = it * 524288 + blockIdx.x * 256 + threadIdx.x;  // float4 units
            const float4* src; u16* dst; int off;
            if (gid < 1048576) { src = x; dst = xb; off = gid; }
            else {
                int g = gid - 1048576;
                int sel = g >> 18;
                off = g & 262143;
                src = sel == 0 ? wq : sel == 1 ? wk : sel == 2 ? wv : wo;
                dst = sel == 0 ? wqb : sel == 1 ? wkb : sel == 2 ? wvb : wob;
            }
            float4 f = src[off];
            ushort4 o;
            o.x = f2bf(f.x); o.y = f2bf(f.y); o.z = f2bf(f.z); o.w = f2bf(f.w);
            ((ushort4*)dst)[off] = o;
        }
    } else {
        int wg   = (blockIdx.x - 2048) * 4 + (threadIdx.x >> 6);  // 0..32767
        int lane = threadIdx.x & 63;
        int q     = wg & 2047;
        int wquad = (wg >> 11) & 7;
        int b     = wg >> 14;
        size_t base = ((size_t)(b * 2048 + q)) * 2048 + wquad * 256 + lane;
        #pragma unroll
        for (int i = 0; i < 4; i++) {
            u64 bits = __ballot(M[base + i * 64] != 0);
            if (lane == 0)
                Mb2[(size_t)(b * 32 + wquad * 4 + i) * 2048 + q] = bits;
        }
    }
}

// ---------------------------------------------------------------------------
// Kernel 2: GEMM C[m,n] = sum_k A[m,k]*B[n,k].  128xBN tile, BK=64 as TWO
// independent BK=32 sub-stages. R13 2-phase double-buffered staging
// (R17-exact: BK=64 dbuf is the measured optimum of this family; R19's
// BK=32 regressed — 16 MFMAs/barrier can't cover the vmcnt drain).
// R14: XCD-aware block swizzle (T1). R16/17: LDS-staged coalesced epilogues.
// MODE 0 (BN=128): fused QKV, B = concat(Wq,Wk,Wv).
//   region 0: Q * 0.125*log2(e) -> row-major [token][1024]
//   region 1: K -> frag-swizzled Kfr (S^T A-frag order)
//   region 2: V -> frag-swizzled Vfr (PV  A-frag order)
// Frag layout (u16): ((((b*16+h)*32+kt)*8 + f)*64 + lane)*8 + j
// MODE 1 (BN=64): out-projection, fp32 out + bias.
// ---------------------------------------------------------------------------
template<int MODE, int BN>
__global__ __launch_bounds__(256) void gemm_k(
    const u16* __restrict__ Ag, const u16* __restrict__ Bg,
    u16* __restrict__ Cq, u16* __restrict__ Kfr, u16* __restrict__ Vfr,
    float* __restrict__ Cf, const float* __restrict__ bias)
{
    constexpr int Kd = 1024;
    constexpr int NB = BN / 32;
    constexpr int BUF = 8192 + BN * 64;      // u16 per buffer (As0|As1|Bs0|Bs1)
    constexpr int GX = (MODE == 0) ? 24 : 16;
    constexpr int NWG = GX * 32;
    __shared__ u16 SM[2 * BUF];
    const int tid  = threadIdx.x;
    const int wave = tid >> 6, lane = tid & 63;
    const int quad = lane >> 4, l16 = lane & 15;

    // XCD swizzle (NWG % 8 == 0): XCD j owns contiguous tile range
    int flat = blockIdx.y * GX + blockIdx.x;
    flat = (flat & 7) * (NWG >> 3) + (flat >> 3);
    const int n0 = (flat % GX) * BN;
    const int m0 = (flat / GX) * 128;

    const int wm = (wave & 1) * 64, wn = (wave >> 1) * (BN / 2);
    f32x4 acc[4][NB];
    #pragma unroll
    for (int i = 0; i < 4; i++)
        #pragma unroll
        for (int j = 0; j < NB; j++)
            acc[i][j] = (f32x4){0.f, 0.f, 0.f, 0.f};

    const int sr = lane >> 2;
    const int sk = (lane & 3) * 8;
    const int ca0 = wave * 2, ca1 = ca0 + 1;
    const u16* gA0 = Ag + (size_t)(m0 + ca0 * 16 + sr) * Kd + sk;
    const u16* gA1 = Ag + (size_t)(m0 + ca1 * 16 + sr) * Kd + sk;
    const int cb0 = (BN == 128) ? wave * 2 : wave;
    const u16* gB0 = Bg + (size_t)(n0 + cb0 * 16 + sr) * Kd + sk;
    const u16* gB1 = (BN == 128) ? Bg + (size_t)(n0 + (cb0 + 1) * 16 + sr) * Kd + sk : nullptr;

    #define GLL16(gp, lp) __builtin_amdgcn_global_load_lds( \
        (const __attribute__((address_space(1))) void*)(gp), \
        (__attribute__((address_space(3))) void*)(lp), 16, 0, 0)

    // stage K-step at k0 into buffer BASE (both BK=32 halves)
    #define STAGE(K0, BASE)                                            \
    {                                                                  \
        u16* As0_ = (BASE);                                            \
        u16* As1_ = (BASE) + 4096;                                     \
        u16* Bs0_ = (BASE) + 8192;                                     \
        u16* Bs1_ = (BASE) + 8192 + BN * 32;                           \
        GLL16(gA0 + (K0), As0_ + ca0 * 512);                           \
        GLL16(gA1 + (K0), As0_ + ca1 * 512);                           \
        GLL16(gB0 + (K0), Bs0_ + cb0 * 512);                           \
        if (BN == 128) GLL16(gB1 + (K0), Bs0_ + (cb0 + 1) * 512);      \
        GLL16(gA0 + (K0) + 32, As1_ + ca0 * 512);                      \
        GLL16(gA1 + (K0) + 32, As1_ + ca1 * 512);                      \
        GLL16(gB0 + (K0) + 32, Bs1_ + cb0 * 512);                      \
        if (BN == 128) GLL16(gB1 + (K0) + 32, Bs1_ + (cb0 + 1) * 512); \
    }

    // prologue: stage tile 0 into buffer 0 (barrier drains vmcnt)
    STAGE(0, SM);
    __syncthreads();

    for (int k0 = 0; k0 < Kd; k0 += 64) {
        u16* cur = SM + ((k0 >> 6) & 1) * BUF;
        u16* nxt = SM + (((k0 >> 6) & 1) ^ 1) * BUF;
        if (k0 + 64 < Kd) STAGE(k0 + 64, nxt);   // prefetch next tile

        #pragma unroll
        for (int kk = 0; kk < 2; kk++) {
            const u16* Ah = cur + (kk ? 4096 : 0);
            const u16* Bh = cur + 8192 + (kk ? BN * 32 : 0);
            bf16x8 af[4], bfr[NB];
            #pragma unroll
            for (int mb = 0; mb < 4; mb++)
                af[mb] = *(const bf16x8*)&Ah[(wm + mb * 16 + l16) * 32 + quad * 8];
            #pragma unroll
            for (int nb = 0; nb < NB; nb++)
                bfr[nb] = *(const bf16x8*)&Bh[(wn + nb * 16 + l16) * 32 + quad * 8];
            #pragma unroll
            for (int mb = 0; mb < 4; mb++)
                #pragma unroll
                for (int nb = 0; nb < NB; nb++)
                    acc[mb][nb] = __builtin_amdgcn_mfma_f32_16x16x32_bf16(
                        af[mb], bfr[nb], acc[mb][nb], 0, 0, 0);
        }
        __syncthreads();   // drains prefetch vmcnt + protects cur for next iter
    }
    #undef STAGE
    #undef GLL16

    if (MODE == 1) {
        // f32 tile 128x68 (pad 4): write (2-way bank, free) + coalesced f32x4
        float* OT = (float*)SM;                // 34.8 KB of 48 KB
        #pragma unroll
        for (int mb = 0; mb < 4; mb++)
            #pragma unroll
            for (int nb = 0; nb < NB; nb++) {
                const int rowb = wm + mb * 16 + quad * 4;
                const int colb = wn + nb * 16 + l16;
                const float bv = bias[n0 + colb];
                #pragma unroll
                for (int r = 0; r < 4; r++)
                    OT[(rowb + r) * 68 + colb] = acc[mb][nb][r] + bv;
            }
        __syncthreads();
        #pragma unroll
        for (int it = 0; it < 8; it++) {
            const int g = (it * 256 + tid) * 4;
            const int row = g >> 6, col = g & 63;
            *(f32x4*)(Cf + (size_t)(m0 + row) * 1024 + n0 + col) =
                *(const f32x4*)(OT + row * 68 + col);
        }
        return;
    }

    const int region = n0 >> 10;   // 0:Q 1:K 2:V — uniform per block
    if (region == 0) {
        // u16 tile 128x132 (pad 4): conflict-free write + coalesced b128
        u16* QT = SM;                          // 33.8 KB of 64 KB
        #pragma unroll
        for (int mb = 0; mb < 4; mb++)
            #pragma unroll
            for (int nb = 0; nb < NB; nb++) {
                const int rowb = wm + mb * 16 + quad * 4;
                const int colb = wn + nb * 16 + l16;
                #pragma unroll
                for (int r = 0; r < 4; r++)
                    QT[(rowb + r) * 132 + colb] =
                        f2bf(acc[mb][nb][r] * 0.18033688011112042f);
            }
        __syncthreads();
        #pragma unroll
        for (int it = 0; it < 8; it++) {       // full 128 rows
            const int g = (it * 256 + tid) * 8;
            const int row = g >> 7, col = g & 127;
            *(bf16x8*)(Cq + (size_t)(m0 + row) * 1024 + (n0 & 1023) + col) =
                *(const bf16x8*)(QT + row * 132 + col);
        }
        return;
    }

    // K/V: LDS transpose into frag order, then coalesced b128 global stores.
    // SM pass layout: ((h2*8 + f)*64 + lane)*8 + j  = 8192 u16 (64 tokens).
    const int bb = m0 >> 11;
    const int kt_base = (m0 & 2047) >> 6;
    const int head_base = (n0 & 1023) >> 6;
    u16* dst = (region == 1) ? Kfr : Vfr;
    #pragma unroll
    for (int pass = 0; pass < 2; pass++) {
        __syncthreads();
        #pragma unroll
        for (int mb = 0; mb < 4; mb++) {
            const int rowb = wm + mb * 16 + quad * 4;     // 0..124 within tile
            if ((rowb >> 6) != pass) continue;            // all 4 r share a pass
            #pragma unroll
            for (int nb = 0; nb < NB; nb++) {
                const int ccol = wn + nb * 16 + l16;      // 0..127 within block
                const int h2 = ccol >> 6, dd = ccol & 63;
                if (region == 1) {
                    const int t = dd >> 4, hik = (dd >> 3) & 1, j = dd & 7;
                    #pragma unroll
                    for (int r = 0; r < 4; r++) {
                        const int km = (rowb + r) & 63;
                        const int f = (km >> 5) * 4 + t;
                        const int lanek = hik * 32 + (km & 31);
                        SM[((h2 * 8 + f) * 64 + lanek) * 8 + j] = f2bf(acc[mb][nb][r]);
                    }
                } else {
                    const int kinb = rowb & 63;
                    const int t = kinb >> 4, hiv = (kinb >> 3) & 1, jb = kinb & 7;
                    const int f = (dd >> 5) * 4 + t;
                    const int lanev = hiv * 32 + (dd & 31);
                    ushort4 pk;
                    pk.x = f2bf(acc[mb][nb][0]); pk.y = f2bf(acc[mb][nb][1]);
                    pk.z = f2bf(acc[mb][nb][2]); pk.w = f2bf(acc[mb][nb][3]);
                    *(ushort4*)&SM[((h2 * 8 + f) * 64 + lanev) * 8 + jb] = pk;
                }
            }
        }
        __syncthreads();
        const int h2g = tid >> 7;
        const int inner = (tid & 127) * 32;
        const size_t gbase =
            ((size_t)(bb * 16 + head_base + h2g) * 32 + kt_base + pass) * 4096;
        #pragma unroll
        for (int c = 0; c < 4; c++)
            *(bf16x8*)&dst[gbase + inner + c * 8] =
                *(const bf16x8*)&SM[h2g * 4096 + inner + c * 8];
    }
}

// ---------------------------------------------------------------------------
// Kernel 3: masked attention, S^T formulation, FULLY FUSED.
// R20: 4-way in-block split-K at 256 threads (R14's split idea, WITHOUT
// R14's register disaster). Block = 64 q-rows (two 32-q tiles shared by all
// 4 waves); kh = wave (8 kt each). Grid 1024 blocks -> 4 blocks/CU
// (VGPR ~112 cap 128, LDS 27 KB) = 16 waves/CU: DOUBLE the TLP that the
// ~22% no-issue fraction was starving for. Per-block frag traffic halves,
// block count doubles -> FETCH unchanged. Merge: kh=1..3 dump f16 partials
// (R14-validated precision) + f32 sums to LDS; kh=0 accumulates, normalizes,
// writes final bf16 AOb. XCD swizzle re-derived for 1024 blocks (bijective).
// Main-loop body byte-identical to R17 (setprio + R9 VALU-diet retained).
// ---------------------------------------------------------------------------
__global__ __launch_bounds__(256, 4) void attn_kernel(
    const u16* __restrict__ Qg, const u16* __restrict__ Kfr, const u16* __restrict__ Vfr,
    const u64* __restrict__ Mb2, u16* __restrict__ AO)
{
    // XCD swizzle over 1024 blocks: XCD j owns flat [j*128,(j+1)*128)
    int flat = (blockIdx.z * 16 + blockIdx.y) * 32 + blockIdx.x;
    flat = (flat & 7) * 128 + (flat >> 3);
    const int qt = flat & 31;         // 0..31 (64 q rows per block)
    const int h  = (flat >> 5) & 15;
    const int b  = flat >> 9;
    const int tid = threadIdx.x, wave = tid >> 6, lane = tid & 63;
    const int l31 = lane & 31, hi = lane >> 5;
    const int kh = wave;              // 4-way k-split (8 kt each)

    const int qrow0 = qt * 64;        // tile a: +l31, tile b: +32+l31
    const int bh    = b * 16 + h;

    // Q B-frags (pre-scaled by 0.125*log2e): n=q=l31, k=hi*8+j (+16t)
    bf16x8 qfa[4], qfb[4];
    {
        const u16* qp = Qg + ((size_t)b * 2048 + qrow0 + l31) * 1024 + h * 64 + hi * 8;
        #pragma unroll
        for (int t = 0; t < 4; t++) qfa[t] = *(const bf16x8*)(qp + t * 16);
        #pragma unroll
        for (int t = 0; t < 4; t++) qfb[t] = *(const bf16x8*)(qp + 32 * 1024 + t * 16);
    }

    // 32-bit frag offsets (arrays are 8 MB): uniform base + u32 voffset
    const u32 fro = (u32)bh * 131072u + (u32)lane * 8u;
    const u64* mp = Mb2 + (size_t)(b * 32) * 2048 + qrow0 + l31;   // + kt*2048 (+32 tile b)

    bf16x8 ones;
    #pragma unroll
    for (int j = 0; j < 8; j++) ones[j] = (short)0x3F80;   // bf16 1.0

    f32x16 oa0, oa1, ob0, ob1, la, lb;
    #pragma unroll
    for (int i = 0; i < 16; i++) {
        oa0[i] = 0.f; oa1[i] = 0.f; ob0[i] = 0.f; ob1[i] = 0.f;
        la[i] = 0.f;  lb[i] = 0.f;
    }

    const int kt0 = kh * 8;
    #pragma unroll 1
    for (int kt = kt0; kt < kt0 + 8; ++kt) {
        const u64 mwa = mp[(size_t)kt * 2048];
        const u64 mwb = mp[(size_t)kt * 2048 + 32];
        const u32 fb = fro + (u32)kt * 4096u;

        #pragma unroll
        for (int ph = 0; ph < 2; ph++) {
            bf16x8 kf[4], vf[4];
            #pragma unroll
            for (int t = 0; t < 4; t++)
                kf[t] = *(const bf16x8*)(Kfr + fb + (u32)(ph * 4 + t) * 512u);
            vf[0] = *(const bf16x8*)(Vfr + fb + (u32)(2 * ph) * 512u);
            vf[1] = *(const bf16x8*)(Vfr + fb + (u32)(2 * ph + 1) * 512u);
            vf[2] = *(const bf16x8*)(Vfr + fb + (u32)(4 + 2 * ph) * 512u);
            vf[3] = *(const bf16x8*)(Vfr + fb + (u32)(4 + 2 * ph + 1) * 512u);

            // mask folded into accumulator init: visible -> 0.0, masked -> -inf
            const u32 mna = ~((ph ? (u32)(mwa >> 32) : (u32)mwa) >> (hi * 4));
            const u32 mnb = ~((ph ? (u32)(mwb >> 32) : (u32)mwb) >> (hi * 4));
            f32x16 sa, sb;
            #pragma unroll
            for (int reg = 0; reg < 16; reg++) {
                const int kb2 = (reg & 3) + 8 * (reg >> 2);
                sa[reg] = __int_as_float(
                    __builtin_amdgcn_sbfe((int)mna, kb2, 1) & (int)0xFF800000);
                sb[reg] = __int_as_float(
                    __builtin_amdgcn_sbfe((int)mnb, kb2, 1) & (int)0xFF800000);
            }
            __builtin_amdgcn_s_setprio(1);
            #pragma unroll
            for (int t = 0; t < 4; t++) {
                sa = __builtin_amdgcn_mfma_f32_32x32x16_bf16(kf[t], qfa[t], sa, 0, 0, 0);
                sb = __builtin_amdgcn_mfma_f32_32x32x16_bf16(kf[t], qfb[t], sb, 0, 0, 0);
            }
            __builtin_amdgcn_s_setprio(0);

            // exp2 + pack pairs to bf16 (truncating) in one v_perm each
            u32 wa[8], wb[8];
            #pragma unroll
            for (int i = 0; i < 8; i++) {
                const float ea0 = __builtin_amdgcn_exp2f(sa[2 * i]);
                const float ea1 = __builtin_amdgcn_exp2f(sa[2 * i + 1]);
                wa[i] = __builtin_amdgcn_perm(__float_as_uint(ea1),
                                              __float_as_uint(ea0), 0x07060302u);
                const float eb0 = __builtin_amdgcn_exp2f(sb[2 * i]);
                const float eb1 = __builtin_amdgcn_exp2f(sb[2 * i + 1]);
                wb[i] = __builtin_amdgcn_perm(__float_as_uint(eb1),
                                              __float_as_uint(eb0), 0x07060302u);
            }

            // P^T B-frags via permlane32_swap (both halves in one instr)
            bf16x8 pba[2], pbb[2];
            #pragma unroll
            for (int fl = 0; fl < 2; fl++) {
                i32x2 a02 = __builtin_amdgcn_permlane32_swap(
                    (int)wa[4 * fl + 0], (int)wa[4 * fl + 2], false, false);
                i32x2 a13 = __builtin_amdgcn_permlane32_swap(
                    (int)wa[4 * fl + 1], (int)wa[4 * fl + 3], false, false);
                union { u32 u[4]; bf16x8 v; } fa;
                fa.u[0] = (u32)a02[0]; fa.u[1] = (u32)a13[0];
                fa.u[2] = (u32)a02[1]; fa.u[3] = (u32)a13[1];
                pba[fl] = fa.v;
                i32x2 b02 = __builtin_amdgcn_permlane32_swap(
                    (int)wb[4 * fl + 0], (int)wb[4 * fl + 2], false, false);
                i32x2 b13 = __builtin_amdgcn_permlane32_swap(
                    (int)wb[4 * fl + 1], (int)wb[4 * fl + 3], false, false);
                union { u32 u[4]; bf16x8 v; } fbu;
                fbu.u[0] = (u32)b02[0]; fbu.u[1] = (u32)b13[0];
                fbu.u[2] = (u32)b02[1]; fbu.u[3] = (u32)b13[1];
                pbb[fl] = fbu.v;
            }

            // O^T += V^T P^T (both q tiles); row-sums via ones-MFMA
            __builtin_amdgcn_s_setprio(1);
            oa0 = __builtin_amdgcn_mfma_f32_32x32x16_bf16(vf[0], pba[0], oa0, 0, 0, 0);
            ob0 = __builtin_amdgcn_mfma_f32_32x32x16_bf16(vf[0], pbb[0], ob0, 0, 0, 0);
            oa0 = __builtin_amdgcn_mfma_f32_32x32x16_bf16(vf[1], pba[1], oa0, 0, 0, 0);
            ob0 = __builtin_amdgcn_mfma_f32_32x32x16_bf16(vf[1], pbb[1], ob0, 0, 0, 0);
            oa1 = __builtin_amdgcn_mfma_f32_32x32x16_bf16(vf[2], pba[0], oa1, 0, 0, 0);
            ob1 = __builtin_amdgcn_mfma_f32_32x32x16_bf16(vf[2], pbb[0], ob1, 0, 0, 0);
            oa1 = __builtin_amdgcn_mfma_f32_32x32x16_bf16(vf[3], pba[1], oa1, 0, 0, 0);
            ob1 = __builtin_amdgcn_mfma_f32_32x32x16_bf16(vf[3], pbb[1], ob1, 0, 0, 0);
            la  = __builtin_amdgcn_mfma_f32_32x32x16_bf16(ones,  pba[0], la,  0, 0, 0);
            lb  = __builtin_amdgcn_mfma_f32_32x32x16_bf16(ones,  pbb[0], lb,  0, 0, 0);
            la  = __builtin_amdgcn_mfma_f32_32x32x16_bf16(ones,  pba[1], la,  0, 0, 0);
            lb  = __builtin_amdgcn_mfma_f32_32x32x16_bf16(ones,  pbb[1], lb,  0, 0, 0);
            __builtin_amdgcn_s_setprio(0);
        }
    }

    // -----------------------------------------------------------------------
    // In-block 4-way split-K merge: kh=1..3 waves dump f16 partials + f32
    // sums to LDS (R14-validated precision); barrier; kh=0 wave accumulates,
    // normalizes 1/l, writes final bf16 AOb[token][h*64+d].
    // Row stride 68 f16 = 136 B -> 2-way bank (free). 27.6 KB total.
    // -----------------------------------------------------------------------
    __shared__ f16   MRGv[3][64][68];        // 26.1 KB
    __shared__ float MRGl[3][64][2];         // 1.5 KB
    if (kh != 0) {
        f16* vp = &MRGv[kh - 1][lane][0];
        #pragma unroll
        for (int i = 0; i < 4; i++) {
            f16x4 p0, p1, p2, p3;
            #pragma unroll
            for (int r = 0; r < 4; r++) {
                p0[r] = (f16)oa0[4 * i + r];
                p1[r] = (f16)oa1[4 * i + r];
                p2[r] = (f16)ob0[4 * i + r];
                p3[r] = (f16)ob1[4 * i + r];
            }
            *(f16x4*)(vp +      4 * i) = p0;
            *(f16x4*)(vp + 16 + 4 * i) = p1;
            *(f16x4*)(vp + 32 + 4 * i) = p2;
            *(f16x4*)(vp + 48 + 4 * i) = p3;
        }
        MRGl[kh - 1][lane][0] = la[0];
        MRGl[kh - 1][lane][1] = lb[0];
    }
    __syncthreads();
    if (kh == 0) {
        float lA = la[0], lB = lb[0];
        #pragma unroll
        for (int s = 0; s < 3; s++) {
            const f16* vp = &MRGv[s][lane][0];
            #pragma unroll
            for (int i = 0; i < 4; i++) {
                f16x4 v0 = *(const f16x4*)(vp +      4 * i);
                f16x4 v1 = *(const f16x4*)(vp + 16 + 4 * i);
                f16x4 v2 = *(const f16x4*)(vp + 32 + 4 * i);
                f16x4 v3 = *(const f16x4*)(vp + 48 + 4 * i);
                #pragma unroll
                for (int r = 0; r < 4; r++) {
                    oa0[4 * i + r] += (float)v0[r];
                    oa1[4 * i + r] += (float)v1[r];
                    ob0[4 * i + r] += (float)v2[r];
                    ob1[4 * i + r] += (float)v3[r];
                }
            }
            lA += MRGl[s][lane][0];
            lB += MRGl[s][lane][1];
        }
        const float invA = 1.0f / lA;
        const float invB = 1.0f / lB;
        const size_t qbase = ((size_t)b * 2048 + qrow0 + l31) * 1024 + h * 64;
        #pragma unroll
        for (int tile = 0; tile < 2; tile++) {
            #pragma unroll
            for (int g = 0; g < 4; g++) {
                const int d0 = tile * 32 + g * 8 + hi * 4;
                ushort4 pa, pb;
                #pragma unroll
                for (int r = 0; r < 4; r++) {
                    const int reg = g * 4 + r;
                    const float va = (tile == 0 ? oa0[reg] : oa1[reg]) * invA;
                    const float vb = (tile == 0 ? ob0[reg] : ob1[reg]) * invB;
                    ((u16*)&pa)[r] = f2bf(va);
                    ((u16*)&pb)[r] = f2bf(vb);
                }
                *(ushort4*)&AO[qbase + d0] = pa;
                *(ushort4*)&AO[qbase + (size_t)32 * 1024 + d0] = pb;
            }
        }
    }
}

// ---------------------------------------------------------------------------
extern "C" void kernel_launch(void* const* d_in, const int* in_sizes, int n_in,
                              void* d_out, int out_size, void* d_ws, size_t ws_size,
                              hipStream_t stream)
{
    const float* x  = (const float*)d_in[0];
    const int*   Mm = (const int*)d_in[1];
    const float* Wq = (const float*)d_in[2];
    const float* Wk = (const float*)d_in[3];
    const float* Wv = (const float*)d_in[4];
    const float* Wo = (const float*)d_in[5];
    const float* bo = (const float*)d_in[6];
    float* out = (float*)d_out;

    // workspace layout (u16 elements), ~53 MB total
    u16* ws  = (u16*)d_ws;
    u16* xb  = ws;                 // 4194304
    u16* wqb = xb  + 4194304;      // 1048576 (wq|wk|wv contiguous = 3072x1024)
    u16* wkb = wqb + 1048576;
    u16* wvb = wkb + 1048576;
    u16* wob = wvb + 1048576;
    u16* Qb  = wob + 1048576;      // 4194304 (pre-scaled by 0.125*log2e)
    u16* Kfr = Qb  + 4194304;      // 4194304 frag-swizzled K
    u16* Vfr = Kfr + 4194304;      // 4194304 frag-swizzled V
    u16* AOb = Vfr + 4194304;      // 4194304
    u64* Mb2 = (u64*)(AOb + 4194304);          // 131072 u64 = 1 MB

    prep_kernel<<<10240, 256, 0, stream>>>(
        (const float4*)x, (const float4*)Wq, (const float4*)Wk,
        (const float4*)Wv, (const float4*)Wo, xb, wqb, wkb, wvb, wob,
        Mm, Mb2);

    dim3 g1(24, 32, 1);  // N=3072/128, M=4096/128 — fused QKV
    gemm_k<0, 128><<<g1, 256, 0, stream>>>(xb, wqb, Qb, Kfr, Vfr, nullptr, nullptr);

    dim3 g2(32, 16, 2);  // qt, H, B — 1024 four-wave blocks, 4-way fused merge
    attn_kernel<<<g2, 256, 0, stream>>>(Qb, Kfr, Vfr, Mb2, AOb);

    dim3 g3(16, 32, 1);  // N/64, M/128 — 512 blocks
    gemm_k<1, 64><<<g3, 256, 0, stream>>>(AOb, wob, nullptr, nullptr, nullptr,
                                          out, bo);
}

// Round 13
// 210.621 us; speedup vs baseline: 2.7486x; 2.7486x over previous
//
#include <hip/hip_runtime.h>
#include <hip/hip_bf16.h>

// Problem constants: B=2, S=2048, D=1024, H=16, HD=64
typedef unsigned short u16;
typedef unsigned int u32;
typedef unsigned long long u64;
typedef _Float16 f16;
typedef __attribute__((__ext_vector_type__(4))) _Float16 f16x4;  // 8B
typedef __attribute__((__ext_vector_type__(8))) short bf16x8;    // 8 bf16 (4 VGPRs)
typedef __attribute__((__ext_vector_type__(4))) float f32x4;     // 16x16 C/D frag
typedef __attribute__((__ext_vector_type__(16))) float f32x16;   // 32x32 C/D frag
typedef __attribute__((__ext_vector_type__(2))) int i32x2;

__device__ __forceinline__ u16 f2bf(float f) {
    u32 u = __float_as_uint(f);
    return (u16)((u + 0x7fffu + ((u >> 16) & 1u)) >> 16);  // RNE
}

// ---------------------------------------------------------------------------
// Kernel 1 (fused): blocks 0..2047 = fp32->bf16 cvt of x + weights (x4
// grid-stride); blocks 2048..10239 = pack M into transposed bitmask, 4
// ballot-words per wave.
// Mb2[(b*32+w)*2048+q] bit i = (M[b][q][w*64+i] != 0).
// ---------------------------------------------------------------------------
__global__ __launch_bounds__(256) void prep_kernel(
    const float4* __restrict__ x,  const float4* __restrict__ wq,
    const float4* __restrict__ wk, const float4* __restrict__ wv,
    const float4* __restrict__ wo,
    u16* __restrict__ xb, u16* __restrict__ wqb, u16* __restrict__ wkb,
    u16* __restrict__ wvb, u16* __restrict__ wob,
    const int* __restrict__ M, u64* __restrict__ Mb2)
{
    if (blockIdx.x < 2048) {
        #pragma unroll
        for (int it = 0; it < 4; it++) {
            int gid = it * 524288 + blockIdx.x * 256 + threadIdx.x;  // float4 units
            const float4* src; u16* dst; int off;
            if (gid < 1048576) { src = x; dst = xb; off = gid; }
            else {
                int g = gid - 1048576;
                int sel = g >> 18;
                off = g & 262143;
                src = sel == 0 ? wq : sel == 1 ? wk : sel == 2 ? wv : wo;
                dst = sel == 0 ? wqb : sel == 1 ? wkb : sel == 2 ? wvb : wob;
            }
            float4 f = src[off];
            ushort4 o;
            o.x = f2bf(f.x); o.y = f2bf(f.y); o.z = f2bf(f.z); o.w = f2bf(f.w);
            ((ushort4*)dst)[off] = o;
        }
    } else {
        int wg   = (blockIdx.x - 2048) * 4 + (threadIdx.x >> 6);  // 0..32767
        int lane = threadIdx.x & 63;
        int q     = wg & 2047;
        int wquad = (wg >> 11) & 7;
        int b     = wg >> 14;
        size_t base = ((size_t)(b * 2048 + q)) * 2048 + wquad * 256 + lane;
        #pragma unroll
        for (int i = 0; i < 4; i++) {
            u64 bits = __ballot(M[base + i * 64] != 0);
            if (lane == 0)
                Mb2[(size_t)(b * 32 + wquad * 4 + i) * 2048 + q] = bits;
        }
    }
}

// ---------------------------------------------------------------------------
// Kernel 2: GEMM C[m,n] = sum_k A[m,k]*B[n,k].  128xBN tile, BK=64 as TWO
// independent BK=32 sub-stages. R13 2-phase double-buffered staging
// (measured optimum of this family: R19's BK=32 dbuf regressed — 16
// MFMAs/barrier can't cover the vmcnt drain; BK=64's 32 can).
// R14: XCD-aware block swizzle (T1). R16/17: LDS-staged coalesced epilogues.
// MODE 0 (BN=128): fused QKV, B = concat(Wq,Wk,Wv).
//   region 0: Q * 0.125*log2(e) -> row-major [token][1024]
//   region 1: K -> frag-swizzled Kfr (S^T A-frag order)
//   region 2: V -> frag-swizzled Vfr (PV  A-frag order)
// Frag layout (u16): ((((b*16+h)*32+kt)*8 + f)*64 + lane)*8 + j
// MODE 1 (BN=64): out-projection, fp32 out + bias.
// ---------------------------------------------------------------------------
template<int MODE, int BN>
__global__ __launch_bounds__(256) void gemm_k(
    const u16* __restrict__ Ag, const u16* __restrict__ Bg,
    u16* __restrict__ Cq, u16* __restrict__ Kfr, u16* __restrict__ Vfr,
    float* __restrict__ Cf, const float* __restrict__ bias)
{
    constexpr int Kd = 1024;
    constexpr int NB = BN / 32;
    constexpr int BUF = 8192 + BN * 64;      // u16 per buffer (As0|As1|Bs0|Bs1)
    constexpr int GX = (MODE == 0) ? 24 : 16;
    constexpr int NWG = GX * 32;
    __shared__ u16 SM[2 * BUF];
    const int tid  = threadIdx.x;
    const int wave = tid >> 6, lane = tid & 63;
    const int quad = lane >> 4, l16 = lane & 15;

    // XCD swizzle (NWG % 8 == 0): XCD j owns contiguous tile range
    int flat = blockIdx.y * GX + blockIdx.x;
    flat = (flat & 7) * (NWG >> 3) + (flat >> 3);
    const int n0 = (flat % GX) * BN;
    const int m0 = (flat / GX) * 128;

    const int wm = (wave & 1) * 64, wn = (wave >> 1) * (BN / 2);
    f32x4 acc[4][NB];
    #pragma unroll
    for (int i = 0; i < 4; i++)
        #pragma unroll
        for (int j = 0; j < NB; j++)
            acc[i][j] = (f32x4){0.f, 0.f, 0.f, 0.f};

    const int sr = lane >> 2;
    const int sk = (lane & 3) * 8;
    const int ca0 = wave * 2, ca1 = ca0 + 1;
    const u16* gA0 = Ag + (size_t)(m0 + ca0 * 16 + sr) * Kd + sk;
    const u16* gA1 = Ag + (size_t)(m0 + ca1 * 16 + sr) * Kd + sk;
    const int cb0 = (BN == 128) ? wave * 2 : wave;
    const u16* gB0 = Bg + (size_t)(n0 + cb0 * 16 + sr) * Kd + sk;
    const u16* gB1 = (BN == 128) ? Bg + (size_t)(n0 + (cb0 + 1) * 16 + sr) * Kd + sk : nullptr;

    #define GLL16(gp, lp) __builtin_amdgcn_global_load_lds( \
        (const __attribute__((address_space(1))) void*)(gp), \
        (__attribute__((address_space(3))) void*)(lp), 16, 0, 0)

    // stage K-step at k0 into buffer BASE (both BK=32 halves)
    #define STAGE(K0, BASE)                                            \
    {                                                                  \
        u16* As0_ = (BASE);                                            \
        u16* As1_ = (BASE) + 4096;                                     \
        u16* Bs0_ = (BASE) + 8192;                                     \
        u16* Bs1_ = (BASE) + 8192 + BN * 32;                           \
        GLL16(gA0 + (K0), As0_ + ca0 * 512);                           \
        GLL16(gA1 + (K0), As0_ + ca1 * 512);                           \
        GLL16(gB0 + (K0), Bs0_ + cb0 * 512);                           \
        if (BN == 128) GLL16(gB1 + (K0), Bs0_ + (cb0 + 1) * 512);      \
        GLL16(gA0 + (K0) + 32, As1_ + ca0 * 512);                      \
        GLL16(gA1 + (K0) + 32, As1_ + ca1 * 512);                      \
        GLL16(gB0 + (K0) + 32, Bs1_ + cb0 * 512);                      \
        if (BN == 128) GLL16(gB1 + (K0) + 32, Bs1_ + (cb0 + 1) * 512); \
    }

    // prologue: stage tile 0 into buffer 0 (barrier drains vmcnt)
    STAGE(0, SM);
    __syncthreads();

    for (int k0 = 0; k0 < Kd; k0 += 64) {
        u16* cur = SM + ((k0 >> 6) & 1) * BUF;
        u16* nxt = SM + (((k0 >> 6) & 1) ^ 1) * BUF;
        if (k0 + 64 < Kd) STAGE(k0 + 64, nxt);   // prefetch next tile

        #pragma unroll
        for (int kk = 0; kk < 2; kk++) {
            const u16* Ah = cur + (kk ? 4096 : 0);
            const u16* Bh = cur + 8192 + (kk ? BN * 32 : 0);
            bf16x8 af[4], bfr[NB];
            #pragma unroll
            for (int mb = 0; mb < 4; mb++)
                af[mb] = *(const bf16x8*)&Ah[(wm + mb * 16 + l16) * 32 + quad * 8];
            #pragma unroll
            for (int nb = 0; nb < NB; nb++)
                bfr[nb] = *(const bf16x8*)&Bh[(wn + nb * 16 + l16) * 32 + quad * 8];
            #pragma unroll
            for (int mb = 0; mb < 4; mb++)
                #pragma unroll
                for (int nb = 0; nb < NB; nb++)
                    acc[mb][nb] = __builtin_amdgcn_mfma_f32_16x16x32_bf16(
                        af[mb], bfr[nb], acc[mb][nb], 0, 0, 0);
        }
        __syncthreads();   // drains prefetch vmcnt + protects cur for next iter
    }
    #undef STAGE
    #undef GLL16

    if (MODE == 1) {
        // f32 tile 128x68 (pad 4): write (2-way bank, free) + coalesced f32x4
        float* OT = (float*)SM;                // 34.8 KB of 48 KB
        #pragma unroll
        for (int mb = 0; mb < 4; mb++)
            #pragma unroll
            for (int nb = 0; nb < NB; nb++) {
                const int rowb = wm + mb * 16 + quad * 4;
                const int colb = wn + nb * 16 + l16;
                const float bv = bias[n0 + colb];
                #pragma unroll
                for (int r = 0; r < 4; r++)
                    OT[(rowb + r) * 68 + colb] = acc[mb][nb][r] + bv;
            }
        __syncthreads();
        #pragma unroll
        for (int it = 0; it < 8; it++) {
            const int g = (it * 256 + tid) * 4;
            const int row = g >> 6, col = g & 63;
            *(f32x4*)(Cf + (size_t)(m0 + row) * 1024 + n0 + col) =
                *(const f32x4*)(OT + row * 68 + col);
        }
        return;
    }

    const int region = n0 >> 10;   // 0:Q 1:K 2:V — uniform per block
    if (region == 0) {
        // u16 tile 128x132 (pad 4): conflict-free write + coalesced b128
        u16* QT = SM;                          // 33.8 KB of 64 KB
        #pragma unroll
        for (int mb = 0; mb < 4; mb++)
            #pragma unroll
            for (int nb = 0; nb < NB; nb++) {
                const int rowb = wm + mb * 16 + quad * 4;
                const int colb = wn + nb * 16 + l16;
                #pragma unroll
                for (int r = 0; r < 4; r++)
                    QT[(rowb + r) * 132 + colb] =
                        f2bf(acc[mb][nb][r] * 0.18033688011112042f);
            }
        __syncthreads();
        #pragma unroll
        for (int it = 0; it < 8; it++) {       // full 128 rows
            const int g = (it * 256 + tid) * 8;
            const int row = g >> 7, col = g & 127;
            *(bf16x8*)(Cq + (size_t)(m0 + row) * 1024 + (n0 & 1023) + col) =
                *(const bf16x8*)(QT + row * 132 + col);
        }
        return;
    }

    // K/V: LDS transpose into frag order, then coalesced b128 global stores.
    // SM pass layout: ((h2*8 + f)*64 + lane)*8 + j  = 8192 u16 (64 tokens).
    const int bb = m0 >> 11;
    const int kt_base = (m0 & 2047) >> 6;
    const int head_base = (n0 & 1023) >> 6;
    u16* dst = (region == 1) ? Kfr : Vfr;
    #pragma unroll
    for (int pass = 0; pass < 2; pass++) {
        __syncthreads();
        #pragma unroll
        for (int mb = 0; mb < 4; mb++) {
            const int rowb = wm + mb * 16 + quad * 4;     // 0..124 within tile
            if ((rowb >> 6) != pass) continue;            // all 4 r share a pass
            #pragma unroll
            for (int nb = 0; nb < NB; nb++) {
                const int ccol = wn + nb * 16 + l16;      // 0..127 within block
                const int h2 = ccol >> 6, dd = ccol & 63;
                if (region == 1) {
                    const int t = dd >> 4, hik = (dd >> 3) & 1, j = dd & 7;
                    #pragma unroll
                    for (int r = 0; r < 4; r++) {
                        const int km = (rowb + r) & 63;
                        const int f = (km >> 5) * 4 + t;
                        const int lanek = hik * 32 + (km & 31);
                        SM[((h2 * 8 + f) * 64 + lanek) * 8 + j] = f2bf(acc[mb][nb][r]);
                    }
                } else {
                    const int kinb = rowb & 63;
                    const int t = kinb >> 4, hiv = (kinb >> 3) & 1, jb = kinb & 7;
                    const int f = (dd >> 5) * 4 + t;
                    const int lanev = hiv * 32 + (dd & 31);
                    ushort4 pk;
                    pk.x = f2bf(acc[mb][nb][0]); pk.y = f2bf(acc[mb][nb][1]);
                    pk.z = f2bf(acc[mb][nb][2]); pk.w = f2bf(acc[mb][nb][3]);
                    *(ushort4*)&SM[((h2 * 8 + f) * 64 + lanev) * 8 + jb] = pk;
                }
            }
        }
        __syncthreads();
        const int h2g = tid >> 7;
        const int inner = (tid & 127) * 32;
        const size_t gbase =
            ((size_t)(bb * 16 + head_base + h2g) * 32 + kt_base + pass) * 4096;
        #pragma unroll
        for (int c = 0; c < 4; c++)
            *(bf16x8*)&dst[gbase + inner + c * 8] =
                *(const bf16x8*)&SM[h2g * 4096 + inner + c * 8];
    }
}

// ---------------------------------------------------------------------------
// Kernel 3: masked attention, S^T formulation, FULLY FUSED (no merge kernel).
// R17-proven configuration (measured 55.8 us): 256 threads, 4 waves, 2-way
// in-block split-K, XCD block swizzle over 512 blocks.
// REGISTER CEILING (R14+R20 lesson, twice-confirmed): this body's live set
// is ~208 unified VGPR+AGPR regs (112 arch + 96 accum) -> 2 waves/SIMD is
// an ARITHMETIC cap. Any launch_bounds demanding more forces the allocator
// under the accumulator footprint -> total spill (VGPR=64, GB-scale scratch
// traffic, ~8x slowdown). Do not trade registers for waves here.
// R13 setprio + R9 VALU-diet retained.
// ---------------------------------------------------------------------------
__global__ __launch_bounds__(256, 2) void attn_kernel(
    const u16* __restrict__ Qg, const u16* __restrict__ Kfr, const u16* __restrict__ Vfr,
    const u64* __restrict__ Mb2, u16* __restrict__ AO)
{
    // XCD swizzle over 512 blocks: XCD j owns flat [j*64,(j+1)*64) = 4 bh x 16 qt
    int flat = (blockIdx.z * 16 + blockIdx.y) * 16 + blockIdx.x;
    flat = (flat & 7) * 64 + (flat >> 3);
    const int qt = flat & 15;
    const int h  = (flat >> 4) & 15;
    const int b  = flat >> 8;
    const int tid = threadIdx.x, wave = tid >> 6, lane = tid & 63;
    const int l31 = lane & 31, hi = lane >> 5;
    const int pair = wave >> 1;       // q-row half within block
    const int kh   = wave & 1;        // k-tile half (16 kt each)

    const int qrow0 = qt * 128 + pair * 64;   // tile a: +l31, tile b: +32+l31
    const int bh    = b * 16 + h;

    // Q B-frags (pre-scaled by 0.125*log2e): n=q=l31, k=hi*8+j (+16t)
    bf16x8 qfa[4], qfb[4];
    {
        const u16* qp = Qg + ((size_t)b * 2048 + qrow0 + l31) * 1024 + h * 64 + hi * 8;
        #pragma unroll
        for (int t = 0; t < 4; t++) qfa[t] = *(const bf16x8*)(qp + t * 16);
        #pragma unroll
        for (int t = 0; t < 4; t++) qfb[t] = *(const bf16x8*)(qp + 32 * 1024 + t * 16);
    }

    // 32-bit frag offsets (arrays are 8 MB): uniform base + u32 voffset
    const u32 fro = (u32)bh * 131072u + (u32)lane * 8u;
    const u64* mp = Mb2 + (size_t)(b * 32) * 2048 + qrow0 + l31;   // + kt*2048 (+32 tile b)

    bf16x8 ones;
    #pragma unroll
    for (int j = 0; j < 8; j++) ones[j] = (short)0x3F80;   // bf16 1.0

    f32x16 oa0, oa1, ob0, ob1, la, lb;
    #pragma unroll
    for (int i = 0; i < 16; i++) {
        oa0[i] = 0.f; oa1[i] = 0.f; ob0[i] = 0.f; ob1[i] = 0.f;
        la[i] = 0.f;  lb[i] = 0.f;
    }

    const int kt0 = kh * 16;
    #pragma unroll 1
    for (int kt = kt0; kt < kt0 + 16; ++kt) {
        const u64 mwa = mp[(size_t)kt * 2048];
        const u64 mwb = mp[(size_t)kt * 2048 + 32];
        const u32 fb = fro + (u32)kt * 4096u;

        #pragma unroll
        for (int ph = 0; ph < 2; ph++) {
            bf16x8 kf[4], vf[4];
            #pragma unroll
            for (int t = 0; t < 4; t++)
                kf[t] = *(const bf16x8*)(Kfr + fb + (u32)(ph * 4 + t) * 512u);
            vf[0] = *(const bf16x8*)(Vfr + fb + (u32)(2 * ph) * 512u);
            vf[1] = *(const bf16x8*)(Vfr + fb + (u32)(2 * ph + 1) * 512u);
            vf[2] = *(const bf16x8*)(Vfr + fb + (u32)(4 + 2 * ph) * 512u);
            vf[3] = *(const bf16x8*)(Vfr + fb + (u32)(4 + 2 * ph + 1) * 512u);

            // mask folded into accumulator init: visible -> 0.0, masked -> -inf
            const u32 mna = ~((ph ? (u32)(mwa >> 32) : (u32)mwa) >> (hi * 4));
            const u32 mnb = ~((ph ? (u32)(mwb >> 32) : (u32)mwb) >> (hi * 4));
            f32x16 sa, sb;
            #pragma unroll
            for (int reg = 0; reg < 16; reg++) {
                const int kb2 = (reg & 3) + 8 * (reg >> 2);
                sa[reg] = __int_as_float(
                    __builtin_amdgcn_sbfe((int)mna, kb2, 1) & (int)0xFF800000);
                sb[reg] = __int_as_float(
                    __builtin_amdgcn_sbfe((int)mnb, kb2, 1) & (int)0xFF800000);
            }
            __builtin_amdgcn_s_setprio(1);
            #pragma unroll
            for (int t = 0; t < 4; t++) {
                sa = __builtin_amdgcn_mfma_f32_32x32x16_bf16(kf[t], qfa[t], sa, 0, 0, 0);
                sb = __builtin_amdgcn_mfma_f32_32x32x16_bf16(kf[t], qfb[t], sb, 0, 0, 0);
            }
            __builtin_amdgcn_s_setprio(0);

            // exp2 + pack pairs to bf16 (truncating) in one v_perm each
            u32 wa[8], wb[8];
            #pragma unroll
            for (int i = 0; i < 8; i++) {
                const float ea0 = __builtin_amdgcn_exp2f(sa[2 * i]);
                const float ea1 = __builtin_amdgcn_exp2f(sa[2 * i + 1]);
                wa[i] = __builtin_amdgcn_perm(__float_as_uint(ea1),
                                              __float_as_uint(ea0), 0x07060302u);
                const float eb0 = __builtin_amdgcn_exp2f(sb[2 * i]);
                const float eb1 = __builtin_amdgcn_exp2f(sb[2 * i + 1]);
                wb[i] = __builtin_amdgcn_perm(__float_as_uint(eb1),
                                              __float_as_uint(eb0), 0x07060302u);
            }

            // P^T B-frags via permlane32_swap (both halves in one instr)
            bf16x8 pba[2], pbb[2];
            #pragma unroll
            for (int fl = 0; fl < 2; fl++) {
                i32x2 a02 = __builtin_amdgcn_permlane32_swap(
                    (int)wa[4 * fl + 0], (int)wa[4 * fl + 2], false, false);
                i32x2 a13 = __builtin_amdgcn_permlane32_swap(
                    (int)wa[4 * fl + 1], (int)wa[4 * fl + 3], false, false);
                union { u32 u[4]; bf16x8 v; } fa;
                fa.u[0] = (u32)a02[0]; fa.u[1] = (u32)a13[0];
                fa.u[2] = (u32)a02[1]; fa.u[3] = (u32)a13[1];
                pba[fl] = fa.v;
                i32x2 b02 = __builtin_amdgcn_permlane32_swap(
                    (int)wb[4 * fl + 0], (int)wb[4 * fl + 2], false, false);
                i32x2 b13 = __builtin_amdgcn_permlane32_swap(
                    (int)wb[4 * fl + 1], (int)wb[4 * fl + 3], false, false);
                union { u32 u[4]; bf16x8 v; } fbu;
                fbu.u[0] = (u32)b02[0]; fbu.u[1] = (u32)b13[0];
                fbu.u[2] = (u32)b02[1]; fbu.u[3] = (u32)b13[1];
                pbb[fl] = fbu.v;
            }

            // O^T += V^T P^T (both q tiles); row-sums via ones-MFMA
            __builtin_amdgcn_s_setprio(1);
            oa0 = __builtin_amdgcn_mfma_f32_32x32x16_bf16(vf[0], pba[0], oa0, 0, 0, 0);
            ob0 = __builtin_amdgcn_mfma_f32_32x32x16_bf16(vf[0], pbb[0], ob0, 0, 0, 0);
            oa0 = __builtin_amdgcn_mfma_f32_32x32x16_bf16(vf[1], pba[1], oa0, 0, 0, 0);
            ob0 = __builtin_amdgcn_mfma_f32_32x32x16_bf16(vf[1], pbb[1], ob0, 0, 0, 0);
            oa1 = __builtin_amdgcn_mfma_f32_32x32x16_bf16(vf[2], pba[0], oa1, 0, 0, 0);
            ob1 = __builtin_amdgcn_mfma_f32_32x32x16_bf16(vf[2], pbb[0], ob1, 0, 0, 0);
            oa1 = __builtin_amdgcn_mfma_f32_32x32x16_bf16(vf[3], pba[1], oa1, 0, 0, 0);
            ob1 = __builtin_amdgcn_mfma_f32_32x32x16_bf16(vf[3], pbb[1], ob1, 0, 0, 0);
            la  = __builtin_amdgcn_mfma_f32_32x32x16_bf16(ones,  pba[0], la,  0, 0, 0);
            lb  = __builtin_amdgcn_mfma_f32_32x32x16_bf16(ones,  pbb[0], lb,  0, 0, 0);
            la  = __builtin_amdgcn_mfma_f32_32x32x16_bf16(ones,  pba[1], la,  0, 0, 0);
            lb  = __builtin_amdgcn_mfma_f32_32x32x16_bf16(ones,  pbb[1], lb,  0, 0, 0);
            __builtin_amdgcn_s_setprio(0);
        }
    }

    // -----------------------------------------------------------------------
    // In-block split-K merge: kh=1 wave -> LDS; kh=0 wave adds, normalizes,
    // writes final bf16 AOb[token][h*64+d]. Stride 68 keeps b128 alignment.
    // -----------------------------------------------------------------------
    __shared__ float MRG[2 * 64 * 68];       // 34.8 KB
    float* slot = &MRG[(pair * 64 + lane) * 68];
    if (kh == 1) {
        #pragma unroll
        for (int i = 0; i < 4; i++) {
            *(f32x4*)(slot +      4 * i) = (f32x4){oa0[4*i], oa0[4*i+1], oa0[4*i+2], oa0[4*i+3]};
            *(f32x4*)(slot + 16 + 4 * i) = (f32x4){oa1[4*i], oa1[4*i+1], oa1[4*i+2], oa1[4*i+3]};
            *(f32x4*)(slot + 32 + 4 * i) = (f32x4){ob0[4*i], ob0[4*i+1], ob0[4*i+2], ob0[4*i+3]};
            *(f32x4*)(slot + 48 + 4 * i) = (f32x4){ob1[4*i], ob1[4*i+1], ob1[4*i+2], ob1[4*i+3]};
        }
        slot[64] = la[0];
        slot[65] = lb[0];
    }
    __syncthreads();
    if (kh == 0) {
        #pragma unroll
        for (int i = 0; i < 16; i++) {
            oa0[i] += slot[i];
            oa1[i] += slot[16 + i];
            ob0[i] += slot[32 + i];
            ob1[i] += slot[48 + i];
        }
        const float invA = 1.0f / (la[0] + slot[64]);
        const float invB = 1.0f / (lb[0] + slot[65]);
        const size_t qbase = ((size_t)b * 2048 + qrow0 + l31) * 1024 + h * 64;
        #pragma unroll
        for (int tile = 0; tile < 2; tile++) {
            #pragma unroll
            for (int g = 0; g < 4; g++) {
                const int d0 = tile * 32 + g * 8 + hi * 4;
                ushort4 pa, pb;
                #pragma unroll
                for (int r = 0; r < 4; r++) {
                    const int reg = g * 4 + r;
                    const float va = (tile == 0 ? oa0[reg] : oa1[reg]) * invA;
                    const float vb = (tile == 0 ? ob0[reg] : ob1[reg]) * invB;
                    ((u16*)&pa)[r] = f2bf(va);
                    ((u16*)&pb)[r] = f2bf(vb);
                }
                *(ushort4*)&AO[qbase + d0] = pa;
                *(ushort4*)&AO[qbase + (size_t)32 * 1024 + d0] = pb;
            }
        }
    }
}

// ---------------------------------------------------------------------------
extern "C" void kernel_launch(void* const* d_in, const int* in_sizes, int n_in,
                              void* d_out, int out_size, void* d_ws, size_t ws_size,
                              hipStream_t stream)
{
    const float* x  = (const float*)d_in[0];
    const int*   Mm = (const int*)d_in[1];
    const float* Wq = (const float*)d_in[2];
    const float* Wk = (const float*)d_in[3];
    const float* Wv = (const float*)d_in[4];
    const float* Wo = (const float*)d_in[5];
    const float* bo = (const float*)d_in[6];
    float* out = (float*)d_out;

    // workspace layout (u16 elements), ~53 MB total
    u16* ws  = (u16*)d_ws;
    u16* xb  = ws;                 // 4194304
    u16* wqb = xb  + 4194304;      // 1048576 (wq|wk|wv contiguous = 3072x1024)
    u16* wkb = wqb + 1048576;
    u16* wvb = wkb + 1048576;
    u16* wob = wvb + 1048576;
    u16* Qb  = wob + 1048576;      // 4194304 (pre-scaled by 0.125*log2e)
    u16* Kfr = Qb  + 4194304;      // 4194304 frag-swizzled K
    u16* Vfr = Kfr + 4194304;      // 4194304 frag-swizzled V
    u16* AOb = Vfr + 4194304;      // 4194304
    u64* Mb2 = (u64*)(AOb + 4194304);          // 131072 u64 = 1 MB

    prep_kernel<<<10240, 256, 0, stream>>>(
        (const float4*)x, (const float4*)Wq, (const float4*)Wk,
        (const float4*)Wv, (const float4*)Wo, xb, wqb, wkb, wvb, wob,
        Mm, Mb2);

    dim3 g1(24, 32, 1);  // N=3072/128, M=4096/128 — fused QKV
    gemm_k<0, 128><<<g1, 256, 0, stream>>>(xb, wqb, Qb, Kfr, Vfr, nullptr, nullptr);

    dim3 g2(16, 16, 2);  // qt, H, B — 512 four-wave blocks, fused merge
    attn_kernel<<<g2, 256, 0, stream>>>(Qb, Kfr, Vfr, Mb2, AOb);

    dim3 g3(16, 32, 1);  // N/64, M/128 — 512 blocks
    gemm_k<1, 64><<<g3, 256, 0, stream>>>(AOb, wob, nullptr, nullptr, nullptr,
                                          out, bo);
}

// Round 15
// 205.880 us; speedup vs baseline: 2.8119x; 1.0230x over previous
//
#include <hip/hip_runtime.h>
#include <hip/hip_bf16.h>

// Problem constants: B=2, S=2048, D=1024, H=16, HD=64
typedef unsigned short u16;
typedef unsigned int u32;
typedef unsigned long long u64;
typedef _Float16 f16;
typedef __attribute__((__ext_vector_type__(4))) _Float16 f16x4;  // 8B
typedef __attribute__((__ext_vector_type__(8))) short bf16x8;    // 8 bf16 (4 VGPRs)
typedef __attribute__((__ext_vector_type__(4))) float f32x4;     // 16x16 C/D frag
typedef __attribute__((__ext_vector_type__(16))) float f32x16;   // 32x32 C/D frag
typedef __attribute__((__ext_vector_type__(2))) int i32x2;

__device__ __forceinline__ u16 f2bf(float f) {
    u32 u = __float_as_uint(f);
    return (u16)((u + 0x7fffu + ((u >> 16) & 1u)) >> 16);  // RNE
}

// ---------------------------------------------------------------------------
// Kernel 1 (fused): blocks 0..2047 = fp32->bf16 cvt of x + weights (x4
// grid-stride); blocks 2048..10239 = pack M into transposed bitmask, 4
// ballot-words per wave.
// Mb2[(b*32+w)*2048+q] bit i = (M[b][q][w*64+i] != 0).
// ---------------------------------------------------------------------------
__global__ __launch_bounds__(256) void prep_kernel(
    const float4* __restrict__ x,  const float4* __restrict__ wq,
    const float4* __restrict__ wk, const float4* __restrict__ wv,
    const float4* __restrict__ wo,
    u16* __restrict__ xb, u16* __restrict__ wqb, u16* __restrict__ wkb,
    u16* __restrict__ wvb, u16* __restrict__ wob,
    const int* __restrict__ M, u64* __restrict__ Mb2)
{
    if (blockIdx.x < 2048) {
        #pragma unroll
        for (int it = 0; it < 4; it++) {
            int gid = it * 524288 + blockIdx.x * 256 + threadIdx.x;  // float4 units
            const float4* src; u16* dst; int off;
            if (gid < 1048576) { src = x; dst = xb; off = gid; }
            else {
                int g = gid - 1048576;
                int sel = g >> 18;
                off = g & 262143;
                src = sel == 0 ? wq : sel == 1 ? wk : sel == 2 ? wv : wo;
                dst = sel == 0 ? wqb : sel == 1 ? wkb : sel == 2 ? wvb : wob;
            }
            float4 f = src[off];
            ushort4 o;
            o.x = f2bf(f.x); o.y = f2bf(f.y); o.z = f2bf(f.z); o.w = f2bf(f.w);
            ((ushort4*)dst)[off] = o;
        }
    } else {
        int wg   = (blockIdx.x - 2048) * 4 + (threadIdx.x >> 6);  // 0..32767
        int lane = threadIdx.x & 63;
        int q     = wg & 2047;
        int wquad = (wg >> 11) & 7;
        int b     = wg >> 14;
        size_t base = ((size_t)(b * 2048 + q)) * 2048 + wquad * 256 + lane;
        #pragma unroll
        for (int i = 0; i < 4; i++) {
            u64 bits = __ballot(M[base + i * 64] != 0);
            if (lane == 0)
                Mb2[(size_t)(b * 32 + wquad * 4 + i) * 2048 + q] = bits;
        }
    }
}

// ---------------------------------------------------------------------------
// Kernel 2: GEMM C[m,n] = sum_k A[m,k]*B[n,k].  128xBN tile, BK=64 as TWO
// independent BK=32 sub-stages. R13 2-phase double-buffered staging.
// R22 (resubmitted after infra failure): 8-wave (512-thread) blocks — R18
// showed 13.9% occupancy at 4-wave/64KB-LDS (2 blocks/CU = 2 waves/SIMD).
// Halving the per-wave tile (wm=(wave&3)*32, acc[2][NB]) drops the live set
// to ~80-105 unified regs, fitting launch_bounds(512,4)'s 128-reg cap ->
// same 2 blocks/CU but 16 waves/CU (4/SIMD): double the TLP covering the
// 2-phase barrier drain. (R14/R20 register lesson respected: GEMM's small
// accumulator affords this; attn's 208-reg body cannot.)
// R14: XCD-aware block swizzle. R16/17: LDS-staged coalesced epilogues.
// MODE 0 (BN=128): fused QKV, B = concat(Wq,Wk,Wv).
//   region 0: Q * 0.125*log2(e) -> row-major [token][1024]
//   region 1: K -> frag-swizzled Kfr (S^T A-frag order)
//   region 2: V -> frag-swizzled Vfr (PV  A-frag order)
// Frag layout (u16): ((((b*16+h)*32+kt)*8 + f)*64 + lane)*8 + j
// MODE 1 (BN=64): out-projection, fp32 out + bias.
// ---------------------------------------------------------------------------
template<int MODE, int BN>
__global__ __launch_bounds__(512, 4) void gemm_k(
    const u16* __restrict__ Ag, const u16* __restrict__ Bg,
    u16* __restrict__ Cq, u16* __restrict__ Kfr, u16* __restrict__ Vfr,
    float* __restrict__ Cf, const float* __restrict__ bias)
{
    constexpr int Kd = 1024;
    constexpr int NB = BN / 32;
    constexpr int BUF = 8192 + BN * 64;      // u16 per buffer (As0|As1|Bs0|Bs1)
    constexpr int GX = (MODE == 0) ? 24 : 16;
    constexpr int NWG = GX * 32;
    __shared__ u16 SM[2 * BUF];
    const int tid  = threadIdx.x;
    const int wave = tid >> 6, lane = tid & 63;
    const int quad = lane >> 4, l16 = lane & 15;

    // XCD swizzle (NWG % 8 == 0): XCD j owns contiguous tile range
    int flat = blockIdx.y * GX + blockIdx.x;
    flat = (flat & 7) * (NWG >> 3) + (flat >> 3);
    const int n0 = (flat % GX) * BN;
    const int m0 = (flat / GX) * 128;

    // 8-wave decomposition: 4 row-groups x (BN/2)-col-groups
    const int wm = (wave & 3) * 32, wn = (wave >> 2) * (BN / 2);
    f32x4 acc[2][NB];
    #pragma unroll
    for (int i = 0; i < 2; i++)
        #pragma unroll
        for (int j = 0; j < NB; j++)
            acc[i][j] = (f32x4){0.f, 0.f, 0.f, 0.f};

    const int sr = lane >> 2;
    const int sk = (lane & 3) * 8;
    // staging: each wave owns ONE 16-row A chunk; B chunk for 8 (BN=128) or
    // first 4 (BN=64) waves. All branches wave-uniform.
    const u16* gA0 = Ag + (size_t)(m0 + wave * 16 + sr) * Kd + sk;
    const int  cbi = (BN == 128) ? wave : (wave & 3);
    const bool doB = (BN == 128) || (wave < 4);
    const u16* gB0 = Bg + (size_t)(n0 + cbi * 16 + sr) * Kd + sk;

    #define GLL16(gp, lp) __builtin_amdgcn_global_load_lds( \
        (const __attribute__((address_space(1))) void*)(gp), \
        (__attribute__((address_space(3))) void*)(lp), 16, 0, 0)

    // stage K-step at k0 into buffer BASE (both BK=32 halves)
    #define STAGE(K0, BASE)                                            \
    {                                                                  \
        u16* As0_ = (BASE);                                            \
        u16* As1_ = (BASE) + 4096;                                     \
        u16* Bs0_ = (BASE) + 8192;                                     \
        u16* Bs1_ = (BASE) + 8192 + BN * 32;                           \
        GLL16(gA0 + (K0), As0_ + wave * 512);                          \
        GLL16(gA0 + (K0) + 32, As1_ + wave * 512);                     \
        if (doB) {                                                     \
            GLL16(gB0 + (K0), Bs0_ + cbi * 512);                       \
            GLL16(gB0 + (K0) + 32, Bs1_ + cbi * 512);                  \
        }                                                              \
    }

    // prologue: stage tile 0 into buffer 0 (barrier drains vmcnt)
    STAGE(0, SM);
    __syncthreads();

    for (int k0 = 0; k0 < Kd; k0 += 64) {
        u16* cur = SM + ((k0 >> 6) & 1) * BUF;
        u16* nxt = SM + (((k0 >> 6) & 1) ^ 1) * BUF;
        if (k0 + 64 < Kd) STAGE(k0 + 64, nxt);   // prefetch next tile

        #pragma unroll
        for (int kk = 0; kk < 2; kk++) {
            const u16* Ah = cur + (kk ? 4096 : 0);
            const u16* Bh = cur + 8192 + (kk ? BN * 32 : 0);
            bf16x8 af[2], bfr[NB];
            #pragma unroll
            for (int mb = 0; mb < 2; mb++)
                af[mb] = *(const bf16x8*)&Ah[(wm + mb * 16 + l16) * 32 + quad * 8];
            #pragma unroll
            for (int nb = 0; nb < NB; nb++)
                bfr[nb] = *(const bf16x8*)&Bh[(wn + nb * 16 + l16) * 32 + quad * 8];
            #pragma unroll
            for (int mb = 0; mb < 2; mb++)
                #pragma unroll
                for (int nb = 0; nb < NB; nb++)
                    acc[mb][nb] = __builtin_amdgcn_mfma_f32_16x16x32_bf16(
                        af[mb], bfr[nb], acc[mb][nb], 0, 0, 0);
        }
        __syncthreads();   // drains prefetch vmcnt + protects cur for next iter
    }
    #undef STAGE
    #undef GLL16

    if (MODE == 1) {
        // f32 tile 128x68 (pad 4) = 34.8 KB of 48 KB; coalesced f32x4 out
        float* OT = (float*)SM;
        #pragma unroll
        for (int mb = 0; mb < 2; mb++)
            #pragma unroll
            for (int nb = 0; nb < NB; nb++) {
                const int rowb = wm + mb * 16 + quad * 4;
                const int colb = wn + nb * 16 + l16;
                const float bv = bias[n0 + colb];
                #pragma unroll
                for (int r = 0; r < 4; r++)
                    OT[(rowb + r) * 68 + colb] = acc[mb][nb][r] + bv;
            }
        __syncthreads();
        #pragma unroll
        for (int it = 0; it < 4; it++) {
            const int g = (it * 512 + tid) * 4;
            const int row = g >> 6, col = g & 63;
            *(f32x4*)(Cf + (size_t)(m0 + row) * 1024 + n0 + col) =
                *(const f32x4*)(OT + row * 68 + col);
        }
        return;
    }

    const int region = n0 >> 10;   // 0:Q 1:K 2:V — uniform per block
    if (region == 0) {
        // u16 tile 128x132 (pad 4) = 33.8 KB of 64 KB; coalesced b128 out
        u16* QT = SM;
        #pragma unroll
        for (int mb = 0; mb < 2; mb++)
            #pragma unroll
            for (int nb = 0; nb < NB; nb++) {
                const int rowb = wm + mb * 16 + quad * 4;
                const int colb = wn + nb * 16 + l16;
                #pragma unroll
                for (int r = 0; r < 4; r++)
                    QT[(rowb + r) * 132 + colb] =
                        f2bf(acc[mb][nb][r] * 0.18033688011112042f);
            }
        __syncthreads();
        #pragma unroll
        for (int it = 0; it < 4; it++) {
            const int g = (it * 512 + tid) * 8;
            const int row = g >> 7, col = g & 127;
            *(bf16x8*)(Cq + (size_t)(m0 + row) * 1024 + (n0 & 1023) + col) =
                *(const bf16x8*)(QT + row * 132 + col);
        }
        return;
    }

    // K/V: LDS transpose into frag order, then coalesced b128 global stores.
    // SM pass layout: ((h2*8 + f)*64 + lane)*8 + j  = 8192 u16 (64 tokens).
    const int bb = m0 >> 11;
    const int kt_base = (m0 & 2047) >> 6;
    const int head_base = (n0 & 1023) >> 6;
    u16* dst = (region == 1) ? Kfr : Vfr;
    #pragma unroll
    for (int pass = 0; pass < 2; pass++) {
        __syncthreads();
        #pragma unroll
        for (int mb = 0; mb < 2; mb++) {
            const int rowb = wm + mb * 16 + quad * 4;     // 0..124 within tile
            if ((rowb >> 6) != pass) continue;            // all 4 r share a pass
            #pragma unroll
            for (int nb = 0; nb < NB; nb++) {
                const int ccol = wn + nb * 16 + l16;      // 0..127 within block
                const int h2 = ccol >> 6, dd = ccol & 63;
                if (region == 1) {
                    const int t = dd >> 4, hik = (dd >> 3) & 1, j = dd & 7;
                    #pragma unroll
                    for (int r = 0; r < 4; r++) {
                        const int km = (rowb + r) & 63;
                        const int f = (km >> 5) * 4 + t;
                        const int lanek = hik * 32 + (km & 31);
                        SM[((h2 * 8 + f) * 64 + lanek) * 8 + j] = f2bf(acc[mb][nb][r]);
                    }
                } else {
                    const int kinb = rowb & 63;
                    const int t = kinb >> 4, hiv = (kinb >> 3) & 1, jb = kinb & 7;
                    const int f = (dd >> 5) * 4 + t;
                    const int lanev = hiv * 32 + (dd & 31);
                    ushort4 pk;
                    pk.x = f2bf(acc[mb][nb][0]); pk.y = f2bf(acc[mb][nb][1]);
                    pk.z = f2bf(acc[mb][nb][2]); pk.w = f2bf(acc[mb][nb][3]);
                    *(ushort4*)&SM[((h2 * 8 + f) * 64 + lanev) * 8 + jb] = pk;
                }
            }
        }
        __syncthreads();
        const int h2g = tid >> 8;                 // 0..1 (512 threads)
        const int inner = (tid & 255) * 16;
        const size_t gbase =
            ((size_t)(bb * 16 + head_base + h2g) * 32 + kt_base + pass) * 4096;
        #pragma unroll
        for (int c = 0; c < 2; c++)
            *(bf16x8*)&dst[gbase + inner + c * 8] =
                *(const bf16x8*)&SM[h2g * 4096 + inner + c * 8];
    }
}

// ---------------------------------------------------------------------------
// Kernel 3: masked attention, S^T formulation, FULLY FUSED (no merge kernel).
// R17-proven configuration (measured 55.8-57.0 us): 256 threads, 4 waves,
// 2-way in-block split-K, XCD block swizzle over 512 blocks.
// REGISTER CEILING (R14+R20, twice-confirmed): this body's live set is ~208
// unified VGPR+AGPR regs -> 2 waves/SIMD is an ARITHMETIC cap. Do not trade
// registers for waves here. R13 setprio + R9 VALU-diet retained.
// ---------------------------------------------------------------------------
__global__ __launch_bounds__(256, 2) void attn_kernel(
    const u16* __restrict__ Qg, const u16* __restrict__ Kfr, const u16* __restrict__ Vfr,
    const u64* __restrict__ Mb2, u16* __restrict__ AO)
{
    // XCD swizzle over 512 blocks: XCD j owns flat [j*64,(j+1)*64) = 4 bh x 16 qt
    int flat = (blockIdx.z * 16 + blockIdx.y) * 16 + blockIdx.x;
    flat = (flat & 7) * 64 + (flat >> 3);
    const int qt = flat & 15;
    const int h  = (flat >> 4) & 15;
    const int b  = flat >> 8;
    const int tid = threadIdx.x, wave = tid >> 6, lane = tid & 63;
    const int l31 = lane & 31, hi = lane >> 5;
    const int pair = wave >> 1;       // q-row half within block
    const int kh   = wave & 1;        // k-tile half (16 kt each)

    const int qrow0 = qt * 128 + pair * 64;   // tile a: +l31, tile b: +32+l31
    const int bh    = b * 16 + h;

    // Q B-frags (pre-scaled by 0.125*log2e): n=q=l31, k=hi*8+j (+16t)
    bf16x8 qfa[4], qfb[4];
    {
        const u16* qp = Qg + ((size_t)b * 2048 + qrow0 + l31) * 1024 + h * 64 + hi * 8;
        #pragma unroll
        for (int t = 0; t < 4; t++) qfa[t] = *(const bf16x8*)(qp + t * 16);
        #pragma unroll
        for (int t = 0; t < 4; t++) qfb[t] = *(const bf16x8*)(qp + 32 * 1024 + t * 16);
    }

    // 32-bit frag offsets (arrays are 8 MB): uniform base + u32 voffset
    const u32 fro = (u32)bh * 131072u + (u32)lane * 8u;
    const u64* mp = Mb2 + (size_t)(b * 32) * 2048 + qrow0 + l31;   // + kt*2048 (+32 tile b)

    bf16x8 ones;
    #pragma unroll
    for (int j = 0; j < 8; j++) ones[j] = (short)0x3F80;   // bf16 1.0

    f32x16 oa0, oa1, ob0, ob1, la, lb;
    #pragma unroll
    for (int i = 0; i < 16; i++) {
        oa0[i] = 0.f; oa1[i] = 0.f; ob0[i] = 0.f; ob1[i] = 0.f;
        la[i] = 0.f;  lb[i] = 0.f;
    }

    const int kt0 = kh * 16;
    #pragma unroll 1
    for (int kt = kt0; kt < kt0 + 16; ++kt) {
        const u64 mwa = mp[(size_t)kt * 2048];
        const u64 mwb = mp[(size_t)kt * 2048 + 32];
        const u32 fb = fro + (u32)kt * 4096u;

        #pragma unroll
        for (int ph = 0; ph < 2; ph++) {
            bf16x8 kf[4], vf[4];
            #pragma unroll
            for (int t = 0; t < 4; t++)
                kf[t] = *(const bf16x8*)(Kfr + fb + (u32)(ph * 4 + t) * 512u);
            vf[0] = *(const bf16x8*)(Vfr + fb + (u32)(2 * ph) * 512u);
            vf[1] = *(const bf16x8*)(Vfr + fb + (u32)(2 * ph + 1) * 512u);
            vf[2] = *(const bf16x8*)(Vfr + fb + (u32)(4 + 2 * ph) * 512u);
            vf[3] = *(const bf16x8*)(Vfr + fb + (u32)(4 + 2 * ph + 1) * 512u);

            // mask folded into accumulator init: visible -> 0.0, masked -> -inf
            const u32 mna = ~((ph ? (u32)(mwa >> 32) : (u32)mwa) >> (hi * 4));
            const u32 mnb = ~((ph ? (u32)(mwb >> 32) : (u32)mwb) >> (hi * 4));
            f32x16 sa, sb;
            #pragma unroll
            for (int reg = 0; reg < 16; reg++) {
                const int kb2 = (reg & 3) + 8 * (reg >> 2);
                sa[reg] = __int_as_float(
                    __builtin_amdgcn_sbfe((int)mna, kb2, 1) & (int)0xFF800000);
                sb[reg] = __int_as_float(
                    __builtin_amdgcn_sbfe((int)mnb, kb2, 1) & (int)0xFF800000);
            }
            __builtin_amdgcn_s_setprio(1);
            #pragma unroll
            for (int t = 0; t < 4; t++) {
                sa = __builtin_amdgcn_mfma_f32_32x32x16_bf16(kf[t], qfa[t], sa, 0, 0, 0);
                sb = __builtin_amdgcn_mfma_f32_32x32x16_bf16(kf[t], qfb[t], sb, 0, 0, 0);
            }
            __builtin_amdgcn_s_setprio(0);

            // exp2 + pack pairs to bf16 (truncating) in one v_perm each
            u32 wa[8], wb[8];
            #pragma unroll
            for (int i = 0; i < 8; i++) {
                const float ea0 = __builtin_amdgcn_exp2f(sa[2 * i]);
                const float ea1 = __builtin_amdgcn_exp2f(sa[2 * i + 1]);
                wa[i] = __builtin_amdgcn_perm(__float_as_uint(ea1),
                                              __float_as_uint(ea0), 0x07060302u);
                const float eb0 = __builtin_amdgcn_exp2f(sb[2 * i]);
                const float eb1 = __builtin_amdgcn_exp2f(sb[2 * i + 1]);
                wb[i] = __builtin_amdgcn_perm(__float_as_uint(eb1),
                                              __float_as_uint(eb0), 0x07060302u);
            }

            // P^T B-frags via permlane32_swap (both halves in one instr)
            bf16x8 pba[2], pbb[2];
            #pragma unroll
            for (int fl = 0; fl < 2; fl++) {
                i32x2 a02 = __builtin_amdgcn_permlane32_swap(
                    (int)wa[4 * fl + 0], (int)wa[4 * fl + 2], false, false);
                i32x2 a13 = __builtin_amdgcn_permlane32_swap(
                    (int)wa[4 * fl + 1], (int)wa[4 * fl + 3], false, false);
                union { u32 u[4]; bf16x8 v; } fa;
                fa.u[0] = (u32)a02[0]; fa.u[1] = (u32)a13[0];
                fa.u[2] = (u32)a02[1]; fa.u[3] = (u32)a13[1];
                pba[fl] = fa.v;
                i32x2 b02 = __builtin_amdgcn_permlane32_swap(
                    (int)wb[4 * fl + 0], (int)wb[4 * fl + 2], false, false);
                i32x2 b13 = __builtin_amdgcn_permlane32_swap(
                    (int)wb[4 * fl + 1], (int)wb[4 * fl + 3], false, false);
                union { u32 u[4]; bf16x8 v; } fbu;
                fbu.u[0] = (u32)b02[0]; fbu.u[1] = (u32)b13[0];
                fbu.u[2] = (u32)b02[1]; fbu.u[3] = (u32)b13[1];
                pbb[fl] = fbu.v;
            }

            // O^T += V^T P^T (both q tiles); row-sums via ones-MFMA
            __builtin_amdgcn_s_setprio(1);
            oa0 = __builtin_amdgcn_mfma_f32_32x32x16_bf16(vf[0], pba[0], oa0, 0, 0, 0);
            ob0 = __builtin_amdgcn_mfma_f32_32x32x16_bf16(vf[0], pbb[0], ob0, 0, 0, 0);
            oa0 = __builtin_amdgcn_mfma_f32_32x32x16_bf16(vf[1], pba[1], oa0, 0, 0, 0);
            ob0 = __builtin_amdgcn_mfma_f32_32x32x16_bf16(vf[1], pbb[1], ob0, 0, 0, 0);
            oa1 = __builtin_amdgcn_mfma_f32_32x32x16_bf16(vf[2], pba[0], oa1, 0, 0, 0);
            ob1 = __builtin_amdgcn_mfma_f32_32x32x16_bf16(vf[2], pbb[0], ob1, 0, 0, 0);
            oa1 = __builtin_amdgcn_mfma_f32_32x32x16_bf16(vf[3], pba[1], oa1, 0, 0, 0);
            ob1 = __builtin_amdgcn_mfma_f32_32x32x16_bf16(vf[3], pbb[1], ob1, 0, 0, 0);
            la  = __builtin_amdgcn_mfma_f32_32x32x16_bf16(ones,  pba[0], la,  0, 0, 0);
            lb  = __builtin_amdgcn_mfma_f32_32x32x16_bf16(ones,  pbb[0], lb,  0, 0, 0);
            la  = __builtin_amdgcn_mfma_f32_32x32x16_bf16(ones,  pba[1], la,  0, 0, 0);
            lb  = __builtin_amdgcn_mfma_f32_32x32x16_bf16(ones,  pbb[1], lb,  0, 0, 0);
            __builtin_amdgcn_s_setprio(0);
        }
    }

    // -----------------------------------------------------------------------
    // In-block split-K merge: kh=1 wave -> LDS; kh=0 wave adds, normalizes,
    // writes final bf16 AOb[token][h*64+d]. Stride 68 keeps b128 alignment.
    // -----------------------------------------------------------------------
    __shared__ float MRG[2 * 64 * 68];       // 34.8 KB
    float* slot = &MRG[(pair * 64 + lane) * 68];
    if (kh == 1) {
        #pragma unroll
        for (int i = 0; i < 4; i++) {
            *(f32x4*)(slot +      4 * i) = (f32x4){oa0[4*i], oa0[4*i+1], oa0[4*i+2], oa0[4*i+3]};
            *(f32x4*)(slot + 16 + 4 * i) = (f32x4){oa1[4*i], oa1[4*i+1], oa1[4*i+2], oa1[4*i+3]};
            *(f32x4*)(slot + 32 + 4 * i) = (f32x4){ob0[4*i], ob0[4*i+1], ob0[4*i+2], ob0[4*i+3]};
            *(f32x4*)(slot + 48 + 4 * i) = (f32x4){ob1[4*i], ob1[4*i+1], ob1[4*i+2], ob1[4*i+3]};
        }
        slot[64] = la[0];
        slot[65] = lb[0];
    }
    __syncthreads();
    if (kh == 0) {
        #pragma unroll
        for (int i = 0; i < 16; i++) {
            oa0[i] += slot[i];
            oa1[i] += slot[16 + i];
            ob0[i] += slot[32 + i];
            ob1[i] += slot[48 + i];
        }
        const float invA = 1.0f / (la[0] + slot[64]);
        const float invB = 1.0f / (lb[0] + slot[65]);
        const size_t qbase = ((size_t)b * 2048 + qrow0 + l31) * 1024 + h * 64;
        #pragma unroll
        for (int tile = 0; tile < 2; tile++) {
            #pragma unroll
            for (int g = 0; g < 4; g++) {
                const int d0 = tile * 32 + g * 8 + hi * 4;
                ushort4 pa, pb;
                #pragma unroll
                for (int r = 0; r < 4; r++) {
                    const int reg = g * 4 + r;
                    const float va = (tile == 0 ? oa0[reg] : oa1[reg]) * invA;
                    const float vb = (tile == 0 ? ob0[reg] : ob1[reg]) * invB;
                    ((u16*)&pa)[r] = f2bf(va);
                    ((u16*)&pb)[r] = f2bf(vb);
                }
                *(ushort4*)&AO[qbase + d0] = pa;
                *(ushort4*)&AO[qbase + (size_t)32 * 1024 + d0] = pb;
            }
        }
    }
}

// ---------------------------------------------------------------------------
extern "C" void kernel_launch(void* const* d_in, const int* in_sizes, int n_in,
                              void* d_out, int out_size, void* d_ws, size_t ws_size,
                              hipStream_t stream)
{
    const float* x  = (const float*)d_in[0];
    const int*   Mm = (const int*)d_in[1];
    const float* Wq = (const float*)d_in[2];
    const float* Wk = (const float*)d_in[3];
    const float* Wv = (const float*)d_in[4];
    const float* Wo = (const float*)d_in[5];
    const float* bo = (const float*)d_in[6];
    float* out = (float*)d_out;

    // workspace layout (u16 elements), ~53 MB total
    u16* ws  = (u16*)d_ws;
    u16* xb  = ws;                 // 4194304
    u16* wqb = xb  + 4194304;      // 1048576 (wq|wk|wv contiguous = 3072x1024)
    u16* wkb = wqb + 1048576;
    u16* wvb = wkb + 1048576;
    u16* wob = wvb + 1048576;
    u16* Qb  = wob + 1048576;      // 4194304 (pre-scaled by 0.125*log2e)
    u16* Kfr = Qb  + 4194304;      // 4194304 frag-swizzled K
    u16* Vfr = Kfr + 4194304;      // 4194304 frag-swizzled V
    u16* AOb = Vfr + 4194304;      // 4194304
    u64* Mb2 = (u64*)(AOb + 4194304);          // 131072 u64 = 1 MB

    prep_kernel<<<10240, 256, 0, stream>>>(
        (const float4*)x, (const float4*)Wq, (const float4*)Wk,
        (const float4*)Wv, (const float4*)Wo, xb, wqb, wkb, wvb, wob,
        Mm, Mb2);

    dim3 g1(24, 32, 1);  // N=3072/128, M=4096/128 — fused QKV, 8-wave blocks
    gemm_k<0, 128><<<g1, 512, 0, stream>>>(xb, wqb, Qb, Kfr, Vfr, nullptr, nullptr);

    dim3 g2(16, 16, 2);  // qt, H, B — 512 four-wave blocks, fused merge
    attn_kernel<<<g2, 256, 0, stream>>>(Qb, Kfr, Vfr, Mb2, AOb);

    dim3 g3(16, 32, 1);  // N/64, M/128 — 512 blocks, 8-wave
    gemm_k<1, 64><<<g3, 512, 0, stream>>>(AOb, wob, nullptr, nullptr, nullptr,
                                          out, bo);
}